// Round 21
// baseline (892.382 us; speedup 1.0000x reference)
//
#include <hip/hip_runtime.h>

#define NH    20000
#define NF    200000
#define DHOST 64
#define DFLOW 128
#define DHID  256
#define NE    2000000

typedef __attribute__((ext_vector_type(8))) short s16x8;
typedef __attribute__((ext_vector_type(4))) float f32x4;

__device__ __forceinline__ unsigned short f2bf(float x) {
    unsigned u = __builtin_bit_cast(unsigned, x);
    unsigned r = (u + 0x7fffu + ((u >> 16) & 1u)) >> 16;
    return (unsigned short)r;
}
__device__ __forceinline__ float bf2f(unsigned short h) {
    unsigned u = ((unsigned)h) << 16;
    return __builtin_bit_cast(float, u);
}

typedef const __attribute__((address_space(1))) unsigned int guint;
typedef __attribute__((address_space(3))) unsigned int luint;
__device__ __forceinline__ void gld16(const void* g, void* l) {
    __builtin_amdgcn_global_load_lds((guint*)g, (luint*)l, 16, 0, 0);
}

// dequant 8 int8 (packed in uint2) with scale s, accumulate into a[0..7]
__device__ __forceinline__ void dq8(uint2 u, float s, float* a) {
#pragma unroll
    for (int j = 0; j < 4; ++j) {
        a[j]     += s * (float)((signed char)(u.x >> (8 * j)));
        a[4 + j] += s * (float)((signed char)(u.y >> (8 * j)));
    }
}

// ---------------- small utils ----------------
__global__ void zero_k(int* __restrict__ p, int n) {
    int i = blockIdx.x * 256 + threadIdx.x;
    if (i < n) p[i] = 0;
}

// W [K][256] f32 -> Wt [256][K] bf16 ; grid (8, K/32, nmat), block 256
__global__ __launch_bounds__(256) void tpose_k(const float* __restrict__ W, unsigned short* __restrict__ Wt, int K) {
    __shared__ float T[32][33];
    int bx = blockIdx.x, by = blockIdx.y;
    const float* Wz = W + (size_t)blockIdx.z * K * 256;
    unsigned short* Wtz = Wt + (size_t)blockIdx.z * K * 256;
    int tx = threadIdx.x & 31, ty = threadIdx.x >> 5;
#pragma unroll
    for (int i = 0; i < 4; ++i) {
        int k = by * 32 + ty + i * 8;
        T[ty + i * 8][tx] = Wz[(size_t)k * 256 + bx * 32 + tx];
    }
    __syncthreads();
#pragma unroll
    for (int i = 0; i < 4; ++i) {
        int n = bx * 32 + ty + i * 8;
        Wtz[(size_t)n * K + by * 32 + tx] = f2bf(T[tx][ty + i * 8]);
    }
}

// exclusive scan, single block (n <= 1024), 256 threads x 4
__global__ void scan1_k(const int* __restrict__ in, int n, int* __restrict__ out, int* __restrict__ bsum) {
    __shared__ int wsum[4];
    int t = threadIdx.x;
    int lane = t & 63, wave = t >> 6;
    int idx = blockIdx.x * 1024 + t * 4;
    int v[4]; int s = 0;
#pragma unroll
    for (int i = 0; i < 4; ++i) { v[i] = (idx + i < n) ? in[idx + i] : 0; s += v[i]; }
    int inc = s;
#pragma unroll
    for (int off = 1; off < 64; off <<= 1) { int u = __shfl_up(inc, off); if (lane >= off) inc += u; }
    if (lane == 63) wsum[wave] = inc;
    __syncthreads();
    int woff = 0;
    for (int w = 0; w < wave; ++w) woff += wsum[w];
    int ex = woff + inc - s;
#pragma unroll
    for (int i = 0; i < 4; ++i) { if (idx + i < n) out[idx + i] = ex; ex += v[i]; }
    if (t == 255) bsum[blockIdx.x] = woff + inc;
}

// ---------------- bucketed CSR build (both graphs per launch) ----------------
__global__ __launch_bounds__(256) void histAB(const int* __restrict__ dstA, const int* __restrict__ dstB,
                                              int E, int* __restrict__ gbhA, int* __restrict__ gbhB) {
    __shared__ int lh[391];
    const int g = blockIdx.y;
    const int* dst = g ? dstB : dstA;
    int* gbh = g ? gbhB : gbhA;
    const int SH = g ? 6 : 9;
    const int NBKT = g ? 313 : 391;
    for (int b = threadIdx.x; b < NBKT; b += 256) lh[b] = 0;
    __syncthreads();
#pragma unroll
    for (int k = 0; k < 8; ++k) {
        int i = blockIdx.x * 2048 + k * 256 + threadIdx.x;
        if (i < E) atomicAdd(&lh[dst[i] >> SH], 1);
    }
    __syncthreads();
    for (int b = threadIdx.x; b < NBKT; b += 256) if (lh[b]) atomicAdd(&gbh[b], lh[b]);
}

__global__ void initcur_k(int* __restrict__ bko, int* __restrict__ gcur, int nbkt, int E) {
    int i = blockIdx.x * 256 + threadIdx.x;
    if (i < nbkt) gcur[i] = bko[i];
    if (i == nbkt) bko[nbkt] = E;
}

__global__ __launch_bounds__(256) void binpassAB(const int* __restrict__ srcA, const int* __restrict__ dstA,
                                                 const int* __restrict__ srcB, const int* __restrict__ dstB,
                                                 int E, int* __restrict__ gcurA, int* __restrict__ gcurB,
                                                 int* __restrict__ pairsA, int* __restrict__ pairsB) {
    __shared__ int lh[391], resv[391], lc[391];
    const int g = blockIdx.y;
    const int* src = g ? srcB : srcA;
    const int* dst = g ? dstB : dstA;
    int* gcur = g ? gcurB : gcurA;
    int* pairs = g ? pairsB : pairsA;
    const int SH = g ? 6 : 9;
    const int NBKT = g ? 313 : 391;
    const int MSK = (1 << SH) - 1;
    const int tid = threadIdx.x;
    const int e0 = blockIdx.x * 8192;
    for (int b = tid; b < NBKT; b += 256) { lh[b] = 0; lc[b] = 0; }
    __syncthreads();
#pragma unroll 4
    for (int k = 0; k < 32; ++k) {
        int i = e0 + k * 256 + tid;
        if (i < E) atomicAdd(&lh[dst[i] >> SH], 1);
    }
    __syncthreads();
    for (int b = tid; b < NBKT; b += 256) if (lh[b]) resv[b] = atomicAdd(&gcur[b], lh[b]);
    __syncthreads();
#pragma unroll 4
    for (int k = 0; k < 32; ++k) {
        int i = e0 + k * 256 + tid;
        if (i < E) {
            int d = dst[i];
            int b = d >> SH;
            int p = resv[b] + atomicAdd(&lc[b], 1);
            pairs[p] = src[i] | ((d & MSK) << 18);
        }
    }
}

// unified pass D for both graphs in one launch
__global__ __launch_bounds__(256) void csrfinAB(const int* __restrict__ pairsA, const int* __restrict__ bkoA,
                                                const int* __restrict__ pairsB, const int* __restrict__ bkoB,
                                                int NBA, int E,
                                                int* __restrict__ rpA, int* __restrict__ colA,
                                                int* __restrict__ rpB, int* __restrict__ colB) {
    __shared__ int cnt[512], pos[512];
    __shared__ int wsum[4];
    const int tid = threadIdx.x;
    const bool isA = (int)blockIdx.x < NBA;
    const int b = isA ? blockIdx.x : blockIdx.x - NBA;
    const int SH = isA ? 9 : 6;
    const int NPB = isA ? 512 : 64;
    const int N = isA ? NF : NH;
    const int* pairs = isA ? pairsA : pairsB;
    const int* bko = isA ? bkoA : bkoB;
    int* rowptr = isA ? rpA : rpB;
    int* col = isA ? colA : colB;
    const int nb = b << SH;
    const int beg = bko[b], end = bko[b + 1];
    for (int i = tid; i < NPB; i += 256) cnt[i] = 0;
    __syncthreads();
    for (int i = beg + tid; i < end; i += 256) atomicAdd(&cnt[pairs[i] >> 18], 1);
    __syncthreads();
    int lane = tid & 63, wave = tid >> 6;
    if (NPB == 512) {
        int a = cnt[2 * tid], b2 = cnt[2 * tid + 1];
        int s = a + b2, incl = s;
#pragma unroll
        for (int off = 1; off < 64; off <<= 1) { int u = __shfl_up(incl, off); if (lane >= off) incl += u; }
        if (lane == 63) wsum[wave] = incl;
        __syncthreads();
        int woff = 0;
        for (int w = 0; w < wave; ++w) woff += wsum[w];
        int ex = woff + incl - s;
        pos[2 * tid] = ex; pos[2 * tid + 1] = ex + a;
    } else {
        if (tid < NPB) {
            int a = cnt[tid], incl = a;
#pragma unroll
            for (int off = 1; off < 64; off <<= 1) { int u = __shfl_up(incl, off); if (lane >= off) incl += u; }
            pos[tid] = incl - a;
        }
    }
    __syncthreads();
    for (int i = tid; i < NPB; i += 256) {
        int node = nb + i;
        if (node < N) rowptr[node] = beg + pos[i];
    }
    if (tid == 0 && end == E) rowptr[N] = E;
    __syncthreads();
    for (int i = beg + tid; i < end; i += 256) {
        int pk = pairs[i];
        int p = atomicAdd(&pos[pk >> 18], 1);
        col[beg + p] = pk & 0x3FFFF;
    }
}

// ---------------- wave-level fh mean aggregation over int8 table (8-deep) ----------------
__device__ __forceinline__ void agg_node(int w, const signed char* __restrict__ qf,
                                         const float* __restrict__ scl,
                                         const int* __restrict__ rowptr,
                                         const int* __restrict__ col,
                                         unsigned short* __restrict__ outp, int lane) {
    int half = lane >> 5, l5 = lane & 31;
    int beg = rowptr[w], end = rowptr[w + 1];
    int T = end - beg;
    const signed char* base = qf + l5 * 8;
    float a0[8], a1[8], a2[8], a3[8], a4[8], a5[8], a6[8], a7[8];
#pragma unroll
    for (int j = 0; j < 8; ++j) {
        a0[j] = 0.f; a1[j] = 0.f; a2[j] = 0.f; a3[j] = 0.f;
        a4[j] = 0.f; a5[j] = 0.f; a6[j] = 0.f; a7[j] = 0.f;
    }
    int i = beg;
    int nb16 = T >> 4;
    {
        const int* cp = col + beg + half * 8;
        for (int k = 0; k < nb16; ++k) {
            int c0 = cp[k * 16 + 0], c1 = cp[k * 16 + 1], c2 = cp[k * 16 + 2], c3 = cp[k * 16 + 3];
            int c4 = cp[k * 16 + 4], c5 = cp[k * 16 + 5], c6 = cp[k * 16 + 6], c7 = cp[k * 16 + 7];
            uint2 u0 = *reinterpret_cast<const uint2*>(base + (size_t)c0 * DHID);
            uint2 u1 = *reinterpret_cast<const uint2*>(base + (size_t)c1 * DHID);
            uint2 u2 = *reinterpret_cast<const uint2*>(base + (size_t)c2 * DHID);
            uint2 u3 = *reinterpret_cast<const uint2*>(base + (size_t)c3 * DHID);
            uint2 u4 = *reinterpret_cast<const uint2*>(base + (size_t)c4 * DHID);
            uint2 u5 = *reinterpret_cast<const uint2*>(base + (size_t)c5 * DHID);
            uint2 u6 = *reinterpret_cast<const uint2*>(base + (size_t)c6 * DHID);
            uint2 u7 = *reinterpret_cast<const uint2*>(base + (size_t)c7 * DHID);
            float s0 = scl[c0], s1 = scl[c1], s2 = scl[c2], s3 = scl[c3];
            float s4 = scl[c4], s5 = scl[c5], s6 = scl[c6], s7 = scl[c7];
            dq8(u0, s0, a0); dq8(u1, s1, a1); dq8(u2, s2, a2); dq8(u3, s3, a3);
            dq8(u4, s4, a4); dq8(u5, s5, a5); dq8(u6, s6, a6); dq8(u7, s7, a7);
        }
    }
    i += nb16 * 16;
    if (end - i >= 8) {
        const int* cp = col + i + half * 4;
        int c0 = cp[0], c1 = cp[1], c2 = cp[2], c3 = cp[3];
        uint2 u0 = *reinterpret_cast<const uint2*>(base + (size_t)c0 * DHID);
        uint2 u1 = *reinterpret_cast<const uint2*>(base + (size_t)c1 * DHID);
        uint2 u2 = *reinterpret_cast<const uint2*>(base + (size_t)c2 * DHID);
        uint2 u3 = *reinterpret_cast<const uint2*>(base + (size_t)c3 * DHID);
        float s0 = scl[c0], s1 = scl[c1], s2 = scl[c2], s3 = scl[c3];
        dq8(u0, s0, a0); dq8(u1, s1, a1); dq8(u2, s2, a2); dq8(u3, s3, a3);
        i += 8;
    }
    for (int e = i + half; e < end; e += 2) {
        int c = col[e];
        uint2 u = *reinterpret_cast<const uint2*>(base + (size_t)c * DHID);
        dq8(u, scl[c], a0);
    }
    int deg = T > 0 ? T : 1;
    float inv = 1.0f / (float)deg;
    s16x8 o;
#pragma unroll
    for (int j = 0; j < 8; ++j) {
        float s = ((a0[j] + a1[j]) + (a2[j] + a3[j])) + ((a4[j] + a5[j]) + (a6[j] + a7[j]));
        s += __shfl_xor(s, 32);
        o[j] = (short)f2bf(s * inv);
    }
    if (half == 0)
        *reinterpret_cast<s16x8*>(outp + (size_t)w * DHID + l5 * 8) = o;
}

// ---------------- BM=64 MFMA bf16 GEMM family, N fixed at 256 ----------------
__device__ __forceinline__ unsigned swz(unsigned r, unsigned cb) {
    return r * 128u + (cb ^ ((r & 7u) << 4));
}

union SmU {
    struct { char A[64 * 128]; char B[256 * 128]; } st;    // 40 KB staging
    unsigned short tile[64][256];                          // 32 KB postprocess tile
};

// one K=256 pass (4 steps of 64), bf16 A source, acc[2][4]
__device__ __forceinline__ void pass64(const unsigned short* A, const unsigned short* Wt,
                                       int m0, int M, int lane, int wave, int wr, int wc,
                                       f32x4 (&acc)[2][4], SmU& sm) {
    for (int k0 = 0; k0 < DHID; k0 += 64) {
        __syncthreads();
        {
            int r = wave * 8 + (lane >> 3);
            int gr = m0 + r; if (gr >= M) gr = M - 1;
            int gs = (lane & 7) ^ (r & 7);
            gld16(A + (size_t)gr * DHID + k0 + gs * 8, sm.st.A + wave * 1024);
        }
#pragma unroll
        for (int i = 0; i < 4; ++i) {
            int u = wave * 4 + i;
            int nn = u * 8 + (lane >> 3);
            int gs = (lane & 7) ^ (nn & 7);
            gld16(Wt + (size_t)nn * DHID + k0 + gs * 8, sm.st.B + u * 1024);
        }
        __syncthreads();
#pragma unroll
        for (int kk = 0; kk < 2; ++kk) {
            s16x8 ar[2], br[4];
            unsigned colb = (unsigned)(kk * 64 + (lane >> 4) * 16);
#pragma unroll
            for (int mf = 0; mf < 2; ++mf)
                ar[mf] = *reinterpret_cast<const s16x8*>(sm.st.A + swz((unsigned)(wr * 32 + mf * 16 + (lane & 15)), colb));
#pragma unroll
            for (int nf = 0; nf < 4; ++nf)
                br[nf] = *reinterpret_cast<const s16x8*>(sm.st.B + swz((unsigned)(wc * 64 + nf * 16 + (lane & 15)), colb));
#pragma unroll
            for (int mf = 0; mf < 2; ++mf)
#pragma unroll
                for (int nf = 0; nf < 4; ++nf)
                    acc[mf][nf] = __builtin_amdgcn_mfma_f32_16x16x32_bf16(ar[mf], br[nf], acc[mf][nf], 0, 0, 0);
        }
    }
}

// shared epilogue: POST=0 direct bf16; POST=1 tile -> bf16 + int8; POST=2 tile -> int8 only
template<int ACT, int POST>
__device__ __forceinline__ void epi64(f32x4 (&acc)[2][4], const float* bias, SmU& sm,
                                      int m0, int M, int lane, int wave, int wr, int wc,
                                      unsigned short* outp, signed char* q, float* scl) {
    const int col0 = wc * 64 + (lane & 15);
    float bc[4];
#pragma unroll
    for (int nf = 0; nf < 4; ++nf) bc[nf] = bias[col0 + nf * 16];
    if (POST == 0) {
#pragma unroll
        for (int mf = 0; mf < 2; ++mf) {
            int row = m0 + wr * 32 + mf * 16 + (lane >> 4) * 4;
#pragma unroll
            for (int j = 0; j < 4; ++j) {
                if (row + j < M) {
#pragma unroll
                    for (int nf = 0; nf < 4; ++nf) {
                        float v = acc[mf][nf][j] + bc[nf];
                        if (ACT == 1) v = fmaxf(v, 0.0f);
                        else if (ACT == 2) v = v > 0.0f ? v : 0.01f * v;
                        outp[(size_t)(row + j) * DHID + col0 + nf * 16] = f2bf(v);
                    }
                }
            }
        }
        return;
    }
    __syncthreads();   // staging reads done before tile overwrites the union
#pragma unroll
    for (int mf = 0; mf < 2; ++mf) {
        int rl = wr * 32 + mf * 16 + (lane >> 4) * 4;
#pragma unroll
        for (int j = 0; j < 4; ++j)
#pragma unroll
            for (int nf = 0; nf < 4; ++nf) {
                float v = acc[mf][nf][j] + bc[nf];
                if (ACT == 1) v = fmaxf(v, 0.0f);
                else if (ACT == 2) v = v > 0.0f ? v : 0.01f * v;
                sm.tile[rl + j][col0 + nf * 16] = f2bf(v);
            }
    }
    __syncthreads();
    const int half = lane >> 5, l5 = lane & 31;
    for (int t = 0; t < 4; ++t) {
        int local = wave * 8 + half * 4 + t;
        int node = m0 + local;
        s16x8 tr = *reinterpret_cast<const s16x8*>(&sm.tile[local][l5 * 8]);
        float v[8]; float m = 0.0f;
#pragma unroll
        for (int j = 0; j < 8; ++j) { v[j] = bf2f((unsigned short)tr[j]); m = fmaxf(m, fabsf(v[j])); }
#pragma unroll
        for (int off = 1; off < 32; off <<= 1) m = fmaxf(m, __shfl_xor(m, off));
        if (node < M) {
            if (POST == 1)
                *reinterpret_cast<s16x8*>(outp + (size_t)node * DHID + l5 * 8) = tr;
            float si = (m > 0.0f) ? 127.0f / m : 0.0f;
            if (l5 == 0) scl[node] = m * (1.0f / 127.0f);
            uint2 pk;
            pk.x = ((unsigned)((int)__builtin_rintf(v[0] * si) & 255))
                 | ((unsigned)((int)__builtin_rintf(v[1] * si) & 255) << 8)
                 | ((unsigned)((int)__builtin_rintf(v[2] * si) & 255) << 16)
                 | ((unsigned)((int)__builtin_rintf(v[3] * si) & 255) << 24);
            pk.y = ((unsigned)((int)__builtin_rintf(v[4] * si) & 255))
                 | ((unsigned)((int)__builtin_rintf(v[5] * si) & 255) << 8)
                 | ((unsigned)((int)__builtin_rintf(v[6] * si) & 255) << 16)
                 | ((unsigned)((int)__builtin_rintf(v[7] * si) & 255) << 24);
            *reinterpret_cast<uint2*>(q + (size_t)node * DHID + l5 * 8) = pk;
        }
    }
}

template<int ACT, int FUSE, int POST>
__global__ __launch_bounds__(512) void mgemm64(const unsigned short* A1, const unsigned short* W1t,
                                               const float* __restrict__ bias,
                                               const unsigned short* A2, const unsigned short* W2t,
                                               unsigned short* outp, signed char* q, float* scl, int M) {
    __shared__ SmU sm;
    const int tid = threadIdx.x;
    const int lane = tid & 63, wave = tid >> 6;
    const int wr = wave >> 2, wc = wave & 3;
    const int m0 = blockIdx.x * 64;
    f32x4 acc[2][4];
#pragma unroll
    for (int a = 0; a < 2; ++a)
#pragma unroll
        for (int b = 0; b < 4; ++b) acc[a][b] = (f32x4)0.0f;
    pass64(A1, W1t, m0, M, lane, wave, wr, wc, acc, sm);
    if (FUSE) pass64(A2, W2t, m0, M, lane, wave, wr, wc, acc, sm);
    epi64<ACT, POST>(acc, bias, sm, m0, M, lane, wave, wr, wc, outp, q, scl);
}

// f32-A input projection, BM=64, K1 in {64,128}
template<int K1, int ACT, int POST>
__global__ __launch_bounds__(512) void mgemm64_f32(const float* __restrict__ A1, const unsigned short* W1t,
                                                   const float* __restrict__ bias,
                                                   unsigned short* outp, signed char* q, float* scl, int M) {
    __shared__ SmU sm;
    const int tid = threadIdx.x;
    const int lane = tid & 63, wave = tid >> 6;
    const int wr = wave >> 2, wc = wave & 3;
    const int m0 = blockIdx.x * 64;
    f32x4 acc[2][4];
#pragma unroll
    for (int a = 0; a < 2; ++a)
#pragma unroll
        for (int b = 0; b < 4; ++b) acc[a][b] = (f32x4)0.0f;

    for (int k0 = 0; k0 < K1; k0 += 64) {
        __syncthreads();
        {
            int r = tid >> 3, gc = tid & 7;
            int gr = m0 + r; if (gr >= M) gr = M - 1;
            const float* src = A1 + (size_t)gr * K1 + k0 + gc * 8;
            float4 v0 = *reinterpret_cast<const float4*>(src);
            float4 v1 = *reinterpret_cast<const float4*>(src + 4);
            s16x8 o;
            o[0] = (short)f2bf(v0.x); o[1] = (short)f2bf(v0.y);
            o[2] = (short)f2bf(v0.z); o[3] = (short)f2bf(v0.w);
            o[4] = (short)f2bf(v1.x); o[5] = (short)f2bf(v1.y);
            o[6] = (short)f2bf(v1.z); o[7] = (short)f2bf(v1.w);
            *reinterpret_cast<s16x8*>(sm.st.A + swz((unsigned)r, (unsigned)(gc * 16))) = o;
        }
#pragma unroll
        for (int i = 0; i < 4; ++i) {
            int u = wave * 4 + i;
            int nn = u * 8 + (lane >> 3);
            int gs = (lane & 7) ^ (nn & 7);
            gld16(W1t + (size_t)nn * K1 + k0 + gs * 8, sm.st.B + u * 1024);
        }
        __syncthreads();
#pragma unroll
        for (int kk = 0; kk < 2; ++kk) {
            s16x8 ar[2], br[4];
            unsigned colb = (unsigned)(kk * 64 + (lane >> 4) * 16);
#pragma unroll
            for (int mf = 0; mf < 2; ++mf)
                ar[mf] = *reinterpret_cast<const s16x8*>(sm.st.A + swz((unsigned)(wr * 32 + mf * 16 + (lane & 15)), colb));
#pragma unroll
            for (int nf = 0; nf < 4; ++nf)
                br[nf] = *reinterpret_cast<const s16x8*>(sm.st.B + swz((unsigned)(wc * 64 + nf * 16 + (lane & 15)), colb));
#pragma unroll
            for (int mf = 0; mf < 2; ++mf)
#pragma unroll
                for (int nf = 0; nf < 4; ++nf)
                    acc[mf][nf] = __builtin_amdgcn_mfma_f32_16x16x32_bf16(ar[mf], br[nf], acc[mf][nf], 0, 0, 0);
        }
    }
    epi64<ACT, POST>(acc, bias, sm, m0, M, lane, wave, wr, wc, outp, q, scl);
}

// ---------------- flow-update body (BM=64, gather over int8 Hq) ----------------
// HEAD=0: write F bf16.  HEAD=1: fuse output head, write logits [M][2] f32.
template<int HEAD>
__device__ __forceinline__ void faq_body(int fb,
                                         const unsigned short* Fin, const unsigned short* Wrt,
                                         const float* __restrict__ bias,
                                         const signed char* __restrict__ Hq,
                                         const float* __restrict__ sclH,
                                         const int* __restrict__ rowptr,
                                         const int* __restrict__ colv,
                                         unsigned short* Fout,
                                         const float* __restrict__ linW,
                                         const float* __restrict__ linb,
                                         float* __restrict__ outHead, int M,
                                         SmU& sm, int lane, int wave) {
    const int wr = wave >> 2, wc = wave & 3;
    const int m0 = fb * 64;
    f32x4 acc[2][4];
#pragma unroll
    for (int a = 0; a < 2; ++a)
#pragma unroll
        for (int b = 0; b < 4; ++b) acc[a][b] = (f32x4)0.0f;

    pass64(Fin, Wrt, m0, M, lane, wave, wr, wc, acc, sm);
    __syncthreads();   // staging reads done before tile overwrites the union

    const int col0 = wc * 64 + (lane & 15);
    float bc[4];
#pragma unroll
    for (int nf = 0; nf < 4; ++nf) bc[nf] = bias[col0 + nf * 16];
#pragma unroll
    for (int mf = 0; mf < 2; ++mf) {
        int rl = wr * 32 + mf * 16 + (lane >> 4) * 4;
#pragma unroll
        for (int j = 0; j < 4; ++j)
#pragma unroll
            for (int nf = 0; nf < 4; ++nf)
                sm.tile[rl + j][col0 + nf * 16] = f2bf(acc[mf][nf][j] + bc[nf]);
    }
    __syncthreads();

    const int half = lane >> 5, l5 = lane & 31;
    const signed char* base = Hq + l5 * 8;
    float w0[8], w1[8], hb0 = 0.0f, hb1 = 0.0f;
    if (HEAD) {
#pragma unroll
        for (int j = 0; j < 8; ++j) {
            w0[j] = linW[(l5 * 8 + j) * 2 + 0];
            w1[j] = linW[(l5 * 8 + j) * 2 + 1];
        }
        hb0 = linb[0]; hb1 = linb[1];
    }
    for (int t = 0; t < 8; ++t) {
        int local = wave * 8 + t;
        int node = m0 + local;
        if (node >= M) break;
        int beg = rowptr[node], end = rowptr[node + 1];
        int T = end - beg;
        int nb8 = T >> 3;
        float a0[8], a1[8], a2[8], a3[8];
#pragma unroll
        for (int j = 0; j < 8; ++j) { a0[j] = 0.f; a1[j] = 0.f; a2[j] = 0.f; a3[j] = 0.f; }
        const int* cp = colv + beg + half * 4;
        for (int k = 0; k < nb8; ++k) {
            int c0 = cp[k * 8 + 0], c1 = cp[k * 8 + 1], c2 = cp[k * 8 + 2], c3 = cp[k * 8 + 3];
            uint2 u0 = *reinterpret_cast<const uint2*>(base + (size_t)c0 * DHID);
            uint2 u1 = *reinterpret_cast<const uint2*>(base + (size_t)c1 * DHID);
            uint2 u2 = *reinterpret_cast<const uint2*>(base + (size_t)c2 * DHID);
            uint2 u3 = *reinterpret_cast<const uint2*>(base + (size_t)c3 * DHID);
            float s0 = sclH[c0], s1 = sclH[c1], s2 = sclH[c2], s3 = sclH[c3];
            dq8(u0, s0, a0); dq8(u1, s1, a1); dq8(u2, s2, a2); dq8(u3, s3, a3);
        }
        for (int i = beg + nb8 * 8 + half; i < end; i += 2) {
            int c = colv[i];
            uint2 u = *reinterpret_cast<const uint2*>(base + (size_t)c * DHID);
            dq8(u, sclH[c], a0);
        }
        float inv = 1.0f / (float)(T > 0 ? T : 1);
        s16x8 tr = *reinterpret_cast<const s16x8*>(&sm.tile[local][l5 * 8]);
        float v[8];
        s16x8 o;
#pragma unroll
        for (int j = 0; j < 8; ++j) {
            float s = (a0[j] + a1[j]) + (a2[j] + a3[j]);
            s += __shfl_xor(s, 32);
            float x = bf2f((unsigned short)tr[j]) + s * inv;
            x = x > 0.0f ? x : 0.01f * x;
            v[j] = x; o[j] = (short)f2bf(x);
        }
        if (HEAD) {
            float p0 = 0.0f, p1 = 0.0f;
#pragma unroll
            for (int j = 0; j < 8; ++j) { p0 += v[j] * w0[j]; p1 += v[j] * w1[j]; }
#pragma unroll
            for (int off = 1; off < 32; off <<= 1) {
                p0 += __shfl_xor(p0, off);
                p1 += __shfl_xor(p1, off);
            }
            if (lane == 0) {
                outHead[(size_t)node * 2 + 0] = p0 + hb0;
                outHead[(size_t)node * 2 + 1] = p1 + hb1;
            }
        } else {
            if (half == 0)
                *reinterpret_cast<s16x8*>(Fout + (size_t)node * DHID + l5 * 8) = o;
        }
    }
}

// layer-1 flow update + fused head (standalone)
__global__ __launch_bounds__(512) void mgemm_fah(const unsigned short* Fin, const unsigned short* Wrt,
                                                 const float* __restrict__ bias,
                                                 const signed char* __restrict__ Hq,
                                                 const float* __restrict__ sclH,
                                                 const int* __restrict__ rowptr,
                                                 const int* __restrict__ colv,
                                                 const float* __restrict__ linW,
                                                 const float* __restrict__ linb,
                                                 float* __restrict__ outHead, int M) {
    __shared__ SmU sm;
    faq_body<1>(blockIdx.x, Fin, Wrt, bias, Hq, sclH, rowptr, colv, nullptr,
                linW, linb, outHead, M, sm, threadIdx.x & 63, threadIdx.x >> 6);
}

// layer-0 combined: interleaved block roles — 5/9 flow-update (faq), 4/9 fh-agg.
// grid = 9 * 625 = 5625; faq blocks cover NF/64 = 3125, agg blocks cover NH/8 = 2500.
__global__ __launch_bounds__(512) void faq_agg_k(const unsigned short* Fin, const unsigned short* Wrt,
                                                 const float* __restrict__ bias,
                                                 const signed char* __restrict__ Hq,
                                                 const float* __restrict__ sclH,
                                                 const int* __restrict__ rp_hf,
                                                 const int* __restrict__ col_hf,
                                                 unsigned short* Fout,
                                                 const signed char* __restrict__ Fq,
                                                 const float* __restrict__ sclF,
                                                 const int* __restrict__ rp_fh,
                                                 const int* __restrict__ col_fh,
                                                 unsigned short* __restrict__ AggH, int MF) {
    __shared__ SmU sm;
    const int lane = threadIdx.x & 63, wave = threadIdx.x >> 6;
    const int grpb = blockIdx.x / 9, rem = blockIdx.x % 9;
    if (rem < 5) {
        int fb = grpb * 5 + rem;
        faq_body<0>(fb, Fin, Wrt, bias, Hq, sclH, rp_hf, col_hf, Fout,
                    nullptr, nullptr, nullptr, MF, sm, lane, wave);
    } else {
        int w = (grpb * 4 + (rem - 5)) * 8 + wave;
        if (w < NH)
            agg_node(w, Fq, sclF, rp_fh, col_fh, AggH, lane);
    }
}

extern "C" void kernel_launch(void* const* d_in, const int* in_sizes, int n_in,
                              void* d_out, int out_size, void* d_ws, size_t ws_size,
                              hipStream_t stream) {
    const float* x_host  = (const float*)d_in[0];
    const float* x_flow  = (const float*)d_in[1];
    const int*   hf_src  = (const int*)d_in[2];
    const int*   hf_dst  = (const int*)d_in[3];
    const int*   fh_src  = (const int*)d_in[4];
    const int*   fh_dst  = (const int*)d_in[5];
    const float* host_W  = (const float*)d_in[6];
    const float* host_b  = (const float*)d_in[7];
    const float* flow_W  = (const float*)d_in[8];
    const float* flow_b  = (const float*)d_in[9];
    const float* Wl_hf   = (const float*)d_in[10];
    const float* bl_hf   = (const float*)d_in[11];
    const float* Wr_hf   = (const float*)d_in[12];
    const float* Wl_fh   = (const float*)d_in[13];
    const float* bl_fh   = (const float*)d_in[14];
    const float* Wr_fh   = (const float*)d_in[15];
    const float* lin_W   = (const float*)d_in[16];
    const float* lin_b   = (const float*)d_in[17];

    char* ws = (char*)d_ws;
    size_t off = 0;
    auto alloc = [&](size_t bytes) -> char* {
        char* p = ws + off;
        off += (bytes + 255) & ~(size_t)255;
        return p;
    };
    typedef unsigned short u16;
    u16* F     = (u16*)alloc((size_t)NF * DHID * 2);
    u16* H     = (u16*)alloc((size_t)NH * DHID * 2);
    u16* AggH  = (u16*)alloc((size_t)NH * DHID * 2);
    signed char* Fq = (signed char*)alloc((size_t)NF * DHID);
    signed char* Hq = (signed char*)alloc((size_t)NH * DHID);
    float* sclF = (float*)alloc((size_t)NF * 4);
    float* sclH = (float*)alloc((size_t)NH * 4);
    u16* hostWt = (u16*)alloc((size_t)DHID * DHOST * 2);
    u16* flowWt = (u16*)alloc((size_t)DHID * DFLOW * 2);
    u16* WlhfT  = (u16*)alloc((size_t)2 * DHID * DHID * 2);
    u16* WrhfT  = (u16*)alloc((size_t)2 * DHID * DHID * 2);
    u16* WlfhT  = (u16*)alloc((size_t)2 * DHID * DHID * 2);
    u16* WrfhT  = (u16*)alloc((size_t)2 * DHID * DHID * 2);
    float* zbias = (float*)alloc(DHID * 4);
    int* rp_hf  = (int*)alloc((size_t)(NF + 1) * 4);
    int* col_hf = (int*)alloc((size_t)NE * 4);
    int* rp_fh  = (int*)alloc((size_t)(NH + 1) * 4);
    int* col_fh = (int*)alloc((size_t)NE * 4);
    int* pairsA = (int*)alloc((size_t)NE * 4);
    int* pairsB = (int*)alloc((size_t)NE * 4);
    int* gbh2   = (int*)alloc(1024 * 4);
    int* bkoA   = (int*)alloc(513 * 4);
    int* bkoB   = (int*)alloc(513 * 4);
    int* gcurA  = (int*)alloc(512 * 4);
    int* gcurB  = (int*)alloc(512 * 4);
    int* junk   = (int*)alloc(4);
    int* gbhA = gbh2, *gbhB = gbh2 + 512;

    const int NBKT_HF = (NF + 511) / 512;   // 391
    const int NBKT_FH = (NH + 63) / 64;     // 313

    // ---- CSR build, both graphs overlapped ----
    zero_k<<<4, 256, 0, stream>>>(gbh2, 1024);
    histAB<<<dim3((NE + 2047) / 2048, 2), 256, 0, stream>>>(hf_dst, fh_dst, NE, gbhA, gbhB);
    scan1_k<<<1, 256, 0, stream>>>(gbhA, NBKT_HF, bkoA, junk);
    scan1_k<<<1, 256, 0, stream>>>(gbhB, NBKT_FH, bkoB, junk);
    initcur_k<<<2, 256, 0, stream>>>(bkoA, gcurA, NBKT_HF, NE);
    initcur_k<<<2, 256, 0, stream>>>(bkoB, gcurB, NBKT_FH, NE);
    binpassAB<<<dim3((NE + 8191) / 8192, 2), 256, 0, stream>>>(hf_src, hf_dst, fh_src, fh_dst, NE,
                                                               gcurA, gcurB, pairsA, pairsB);
    csrfinAB<<<NBKT_HF + NBKT_FH, 256, 0, stream>>>(pairsA, bkoA, pairsB, bkoB, NBKT_HF, NE,
                                                    rp_hf, col_hf, rp_fh, col_fh);

    // ---- weights to bf16 (transposed); zero bias ----
    zero_k<<<1, 256, 0, stream>>>((int*)zbias, DHID);
    tpose_k<<<dim3(8, DHOST / 32, 1), 256, 0, stream>>>(host_W, hostWt, DHOST);
    tpose_k<<<dim3(8, DFLOW / 32, 1), 256, 0, stream>>>(flow_W, flowWt, DFLOW);
    tpose_k<<<dim3(8, 8, 2), 256, 0, stream>>>(Wl_hf, WlhfT, DHID);
    tpose_k<<<dim3(8, 8, 2), 256, 0, stream>>>(Wr_hf, WrhfT, DHID);
    tpose_k<<<dim3(8, 8, 2), 256, 0, stream>>>(Wl_fh, WlfhT, DHID);
    tpose_k<<<dim3(8, 8, 2), 256, 0, stream>>>(Wr_fh, WrfhT, DHID);

    // ---- input projections (relu); flow also emits int8 Fq for layer-0 fh-agg ----
    mgemm64_f32<DHOST, 1, 0><<<(NH + 63) / 64, 512, 0, stream>>>(x_host, hostWt, host_b, H, nullptr, nullptr, NH);
    mgemm64_f32<DFLOW, 1, 1><<<(NF + 63) / 64, 512, 0, stream>>>(x_flow, flowWt, flow_b, F, Fq, sclF, NF);

    // ---- layer 0 ----
    {
        const u16* wl_hf = WlhfT;
        const u16* wr_hf = WrhfT;
        const u16* wl_fh = WlfhT;
        const u16* wr_fh = WrfhT;

        // Hq = int8(H @ Wl_hf)
        mgemm64<0, 0, 2><<<(NH + 63) / 64, 512, 0, stream>>>(H, wl_hf, zbias, H, wl_hf,
                                                             nullptr, Hq, sclH, NH);
        // combined: flow update (in place on F) CONCURRENT WITH fh-agg (Fq -> AggH)
        faq_agg_k<<<9 * 625, 512, 0, stream>>>(F, wr_hf, bl_hf, Hq, sclH, rp_hf, col_hf, F,
                                               Fq, sclF, rp_fh, col_fh, AggH, NF);
        // host update in place on H
        mgemm64<2, 1, 0><<<(NH + 63) / 64, 512, 0, stream>>>(AggH, wl_fh, bl_fh, H, wr_fh,
                                                             H, nullptr, nullptr, NH);
    }

    // ---- layer 1 (host-side update dead; head fused into flow update) ----
    {
        const u16* wl_hf = WlhfT + (size_t)DHID * DHID;
        const u16* wr_hf = WrhfT + (size_t)DHID * DHID;
        const float* b_hf = bl_hf + DHID;

        mgemm64<0, 0, 2><<<(NH + 63) / 64, 512, 0, stream>>>(H, wl_hf, zbias, H, wl_hf,
                                                             nullptr, Hq, sclH, NH);
        mgemm_fah<<<(NF + 63) / 64, 512, 0, stream>>>(F, wr_hf, b_hf, Hq, sclH,
                                                      rp_hf, col_hf, lin_W, lin_b,
                                                      (float*)d_out, NF);
    }
}

// Round 22
// 731.950 us; speedup vs baseline: 1.2192x; 1.2192x over previous
//
#include <hip/hip_runtime.h>

#define NH    20000
#define NF    200000
#define DHOST 64
#define DFLOW 128
#define DHID  256
#define NE    2000000

typedef __attribute__((ext_vector_type(8))) short s16x8;
typedef __attribute__((ext_vector_type(4))) float f32x4;

__device__ __forceinline__ unsigned short f2bf(float x) {
    unsigned u = __builtin_bit_cast(unsigned, x);
    unsigned r = (u + 0x7fffu + ((u >> 16) & 1u)) >> 16;
    return (unsigned short)r;
}
__device__ __forceinline__ float bf2f(unsigned short h) {
    unsigned u = ((unsigned)h) << 16;
    return __builtin_bit_cast(float, u);
}

typedef const __attribute__((address_space(1))) unsigned int guint;
typedef __attribute__((address_space(3))) unsigned int luint;
__device__ __forceinline__ void gld16(const void* g, void* l) {
    __builtin_amdgcn_global_load_lds((guint*)g, (luint*)l, 16, 0, 0);
}

// dequant 8 int8 (packed in uint2) with scale s, accumulate into a[0..7]
__device__ __forceinline__ void dq8(uint2 u, float s, float* a) {
#pragma unroll
    for (int j = 0; j < 4; ++j) {
        a[j]     += s * (float)((signed char)(u.x >> (8 * j)));
        a[4 + j] += s * (float)((signed char)(u.y >> (8 * j)));
    }
}

// ---------------- small utils ----------------
__global__ void zero_k(int* __restrict__ p, int n) {
    int i = blockIdx.x * 256 + threadIdx.x;
    if (i < n) p[i] = 0;
}

// W [K][256] f32 -> Wt [256][K] bf16 ; grid (8, K/32, nmat), block 256
__global__ __launch_bounds__(256) void tpose_k(const float* __restrict__ W, unsigned short* __restrict__ Wt, int K) {
    __shared__ float T[32][33];
    int bx = blockIdx.x, by = blockIdx.y;
    const float* Wz = W + (size_t)blockIdx.z * K * 256;
    unsigned short* Wtz = Wt + (size_t)blockIdx.z * K * 256;
    int tx = threadIdx.x & 31, ty = threadIdx.x >> 5;
#pragma unroll
    for (int i = 0; i < 4; ++i) {
        int k = by * 32 + ty + i * 8;
        T[ty + i * 8][tx] = Wz[(size_t)k * 256 + bx * 32 + tx];
    }
    __syncthreads();
#pragma unroll
    for (int i = 0; i < 4; ++i) {
        int n = bx * 32 + ty + i * 8;
        Wtz[(size_t)n * K + by * 32 + tx] = f2bf(T[tx][ty + i * 8]);
    }
}

// exclusive scan, single block (n <= 1024), 256 threads x 4
__global__ void scan1_k(const int* __restrict__ in, int n, int* __restrict__ out, int* __restrict__ bsum) {
    __shared__ int wsum[4];
    int t = threadIdx.x;
    int lane = t & 63, wave = t >> 6;
    int idx = blockIdx.x * 1024 + t * 4;
    int v[4]; int s = 0;
#pragma unroll
    for (int i = 0; i < 4; ++i) { v[i] = (idx + i < n) ? in[idx + i] : 0; s += v[i]; }
    int inc = s;
#pragma unroll
    for (int off = 1; off < 64; off <<= 1) { int u = __shfl_up(inc, off); if (lane >= off) inc += u; }
    if (lane == 63) wsum[wave] = inc;
    __syncthreads();
    int woff = 0;
    for (int w = 0; w < wave; ++w) woff += wsum[w];
    int ex = woff + inc - s;
#pragma unroll
    for (int i = 0; i < 4; ++i) { if (idx + i < n) out[idx + i] = ex; ex += v[i]; }
    if (t == 255) bsum[blockIdx.x] = woff + inc;
}

// ---------------- bucketed CSR build (both graphs per launch) ----------------
__global__ __launch_bounds__(256) void histAB(const int* __restrict__ dstA, const int* __restrict__ dstB,
                                              int E, int* __restrict__ gbhA, int* __restrict__ gbhB) {
    __shared__ int lh[391];
    const int g = blockIdx.y;
    const int* dst = g ? dstB : dstA;
    int* gbh = g ? gbhB : gbhA;
    const int SH = g ? 6 : 9;
    const int NBKT = g ? 313 : 391;
    for (int b = threadIdx.x; b < NBKT; b += 256) lh[b] = 0;
    __syncthreads();
#pragma unroll
    for (int k = 0; k < 8; ++k) {
        int i = blockIdx.x * 2048 + k * 256 + threadIdx.x;
        if (i < E) atomicAdd(&lh[dst[i] >> SH], 1);
    }
    __syncthreads();
    for (int b = threadIdx.x; b < NBKT; b += 256) if (lh[b]) atomicAdd(&gbh[b], lh[b]);
}

__global__ void initcur_k(int* __restrict__ bko, int* __restrict__ gcur, int nbkt, int E) {
    int i = blockIdx.x * 256 + threadIdx.x;
    if (i < nbkt) gcur[i] = bko[i];
    if (i == nbkt) bko[nbkt] = E;
}

__global__ __launch_bounds__(256) void binpassAB(const int* __restrict__ srcA, const int* __restrict__ dstA,
                                                 const int* __restrict__ srcB, const int* __restrict__ dstB,
                                                 int E, int* __restrict__ gcurA, int* __restrict__ gcurB,
                                                 int* __restrict__ pairsA, int* __restrict__ pairsB) {
    __shared__ int lh[391], resv[391], lc[391];
    const int g = blockIdx.y;
    const int* src = g ? srcB : srcA;
    const int* dst = g ? dstB : dstA;
    int* gcur = g ? gcurB : gcurA;
    int* pairs = g ? pairsB : pairsA;
    const int SH = g ? 6 : 9;
    const int NBKT = g ? 313 : 391;
    const int MSK = (1 << SH) - 1;
    const int tid = threadIdx.x;
    const int e0 = blockIdx.x * 8192;
    for (int b = tid; b < NBKT; b += 256) { lh[b] = 0; lc[b] = 0; }
    __syncthreads();
#pragma unroll 4
    for (int k = 0; k < 32; ++k) {
        int i = e0 + k * 256 + tid;
        if (i < E) atomicAdd(&lh[dst[i] >> SH], 1);
    }
    __syncthreads();
    for (int b = tid; b < NBKT; b += 256) if (lh[b]) resv[b] = atomicAdd(&gcur[b], lh[b]);
    __syncthreads();
#pragma unroll 4
    for (int k = 0; k < 32; ++k) {
        int i = e0 + k * 256 + tid;
        if (i < E) {
            int d = dst[i];
            int b = d >> SH;
            int p = resv[b] + atomicAdd(&lc[b], 1);
            pairs[p] = src[i] | ((d & MSK) << 18);
        }
    }
}

// unified pass D for both graphs in one launch
__global__ __launch_bounds__(256) void csrfinAB(const int* __restrict__ pairsA, const int* __restrict__ bkoA,
                                                const int* __restrict__ pairsB, const int* __restrict__ bkoB,
                                                int NBA, int E,
                                                int* __restrict__ rpA, int* __restrict__ colA,
                                                int* __restrict__ rpB, int* __restrict__ colB) {
    __shared__ int cnt[512], pos[512];
    __shared__ int wsum[4];
    const int tid = threadIdx.x;
    const bool isA = (int)blockIdx.x < NBA;
    const int b = isA ? blockIdx.x : blockIdx.x - NBA;
    const int SH = isA ? 9 : 6;
    const int NPB = isA ? 512 : 64;
    const int N = isA ? NF : NH;
    const int* pairs = isA ? pairsA : pairsB;
    const int* bko = isA ? bkoA : bkoB;
    int* rowptr = isA ? rpA : rpB;
    int* col = isA ? colA : colB;
    const int nb = b << SH;
    const int beg = bko[b], end = bko[b + 1];
    for (int i = tid; i < NPB; i += 256) cnt[i] = 0;
    __syncthreads();
    for (int i = beg + tid; i < end; i += 256) atomicAdd(&cnt[pairs[i] >> 18], 1);
    __syncthreads();
    int lane = tid & 63, wave = tid >> 6;
    if (NPB == 512) {
        int a = cnt[2 * tid], b2 = cnt[2 * tid + 1];
        int s = a + b2, incl = s;
#pragma unroll
        for (int off = 1; off < 64; off <<= 1) { int u = __shfl_up(incl, off); if (lane >= off) incl += u; }
        if (lane == 63) wsum[wave] = incl;
        __syncthreads();
        int woff = 0;
        for (int w = 0; w < wave; ++w) woff += wsum[w];
        int ex = woff + incl - s;
        pos[2 * tid] = ex; pos[2 * tid + 1] = ex + a;
    } else {
        if (tid < NPB) {
            int a = cnt[tid], incl = a;
#pragma unroll
            for (int off = 1; off < 64; off <<= 1) { int u = __shfl_up(incl, off); if (lane >= off) incl += u; }
            pos[tid] = incl - a;
        }
    }
    __syncthreads();
    for (int i = tid; i < NPB; i += 256) {
        int node = nb + i;
        if (node < N) rowptr[node] = beg + pos[i];
    }
    if (tid == 0 && end == E) rowptr[N] = E;
    __syncthreads();
    for (int i = beg + tid; i < end; i += 256) {
        int pk = pairs[i];
        int p = atomicAdd(&pos[pk >> 18], 1);
        col[beg + p] = pk & 0x3FFFF;
    }
}

// ---------------- mean aggregation over int8 table, 8-deep (high-degree fh) ----------------
__global__ __launch_bounds__(256) void agg8_q8(const signed char* __restrict__ qf,
                                               const float* __restrict__ scl,
                                               const int* __restrict__ rowptr,
                                               const int* __restrict__ col,
                                               unsigned short* __restrict__ outp, int n) {
    int w = (blockIdx.x << 2) + (threadIdx.x >> 6);
    if (w >= n) return;
    int lane = threadIdx.x & 63;
    int half = lane >> 5, l5 = lane & 31;
    int beg = rowptr[w], end = rowptr[w + 1];
    int T = end - beg;
    const signed char* base = qf + l5 * 8;
    float a0[8], a1[8], a2[8], a3[8], a4[8], a5[8], a6[8], a7[8];
#pragma unroll
    for (int j = 0; j < 8; ++j) {
        a0[j] = 0.f; a1[j] = 0.f; a2[j] = 0.f; a3[j] = 0.f;
        a4[j] = 0.f; a5[j] = 0.f; a6[j] = 0.f; a7[j] = 0.f;
    }
    int i = beg;
    int nb16 = T >> 4;
    {
        const int* cp = col + beg + half * 8;
        for (int k = 0; k < nb16; ++k) {
            int c0 = cp[k * 16 + 0], c1 = cp[k * 16 + 1], c2 = cp[k * 16 + 2], c3 = cp[k * 16 + 3];
            int c4 = cp[k * 16 + 4], c5 = cp[k * 16 + 5], c6 = cp[k * 16 + 6], c7 = cp[k * 16 + 7];
            uint2 u0 = *reinterpret_cast<const uint2*>(base + (size_t)c0 * DHID);
            uint2 u1 = *reinterpret_cast<const uint2*>(base + (size_t)c1 * DHID);
            uint2 u2 = *reinterpret_cast<const uint2*>(base + (size_t)c2 * DHID);
            uint2 u3 = *reinterpret_cast<const uint2*>(base + (size_t)c3 * DHID);
            uint2 u4 = *reinterpret_cast<const uint2*>(base + (size_t)c4 * DHID);
            uint2 u5 = *reinterpret_cast<const uint2*>(base + (size_t)c5 * DHID);
            uint2 u6 = *reinterpret_cast<const uint2*>(base + (size_t)c6 * DHID);
            uint2 u7 = *reinterpret_cast<const uint2*>(base + (size_t)c7 * DHID);
            float s0 = scl[c0], s1 = scl[c1], s2 = scl[c2], s3 = scl[c3];
            float s4 = scl[c4], s5 = scl[c5], s6 = scl[c6], s7 = scl[c7];
            dq8(u0, s0, a0); dq8(u1, s1, a1); dq8(u2, s2, a2); dq8(u3, s3, a3);
            dq8(u4, s4, a4); dq8(u5, s5, a5); dq8(u6, s6, a6); dq8(u7, s7, a7);
        }
    }
    i += nb16 * 16;
    if (end - i >= 8) {
        const int* cp = col + i + half * 4;
        int c0 = cp[0], c1 = cp[1], c2 = cp[2], c3 = cp[3];
        uint2 u0 = *reinterpret_cast<const uint2*>(base + (size_t)c0 * DHID);
        uint2 u1 = *reinterpret_cast<const uint2*>(base + (size_t)c1 * DHID);
        uint2 u2 = *reinterpret_cast<const uint2*>(base + (size_t)c2 * DHID);
        uint2 u3 = *reinterpret_cast<const uint2*>(base + (size_t)c3 * DHID);
        float s0 = scl[c0], s1 = scl[c1], s2 = scl[c2], s3 = scl[c3];
        dq8(u0, s0, a0); dq8(u1, s1, a1); dq8(u2, s2, a2); dq8(u3, s3, a3);
        i += 8;
    }
    for (int e = i + half; e < end; e += 2) {
        int c = col[e];
        uint2 u = *reinterpret_cast<const uint2*>(base + (size_t)c * DHID);
        dq8(u, scl[c], a0);
    }
    int deg = T > 0 ? T : 1;
    float inv = 1.0f / (float)deg;
    s16x8 o;
#pragma unroll
    for (int j = 0; j < 8; ++j) {
        float s = ((a0[j] + a1[j]) + (a2[j] + a3[j])) + ((a4[j] + a5[j]) + (a6[j] + a7[j]));
        s += __shfl_xor(s, 32);
        o[j] = (short)f2bf(s * inv);
    }
    if (half == 0)
        *reinterpret_cast<s16x8*>(outp + (size_t)w * DHID + l5 * 8) = o;
}

// ---------------- BM=64 MFMA bf16 GEMM family, N fixed at 256 ----------------
__device__ __forceinline__ unsigned swz(unsigned r, unsigned cb) {
    return r * 128u + (cb ^ ((r & 7u) << 4));
}

union SmU {
    struct { char A[64 * 128]; char B[256 * 128]; } st;    // 40 KB staging
    unsigned short tile[64][256];                          // 32 KB postprocess tile
};

// one K=256 pass (4 steps of 64), bf16 A source, acc[2][4]
__device__ __forceinline__ void pass64(const unsigned short* A, const unsigned short* Wt,
                                       int m0, int M, int lane, int wave, int wr, int wc,
                                       f32x4 (&acc)[2][4], SmU& sm) {
    for (int k0 = 0; k0 < DHID; k0 += 64) {
        __syncthreads();
        {
            int r = wave * 8 + (lane >> 3);
            int gr = m0 + r; if (gr >= M) gr = M - 1;
            int gs = (lane & 7) ^ (r & 7);
            gld16(A + (size_t)gr * DHID + k0 + gs * 8, sm.st.A + wave * 1024);
        }
#pragma unroll
        for (int i = 0; i < 4; ++i) {
            int u = wave * 4 + i;
            int nn = u * 8 + (lane >> 3);
            int gs = (lane & 7) ^ (nn & 7);
            gld16(Wt + (size_t)nn * DHID + k0 + gs * 8, sm.st.B + u * 1024);
        }
        __syncthreads();
#pragma unroll
        for (int kk = 0; kk < 2; ++kk) {
            s16x8 ar[2], br[4];
            unsigned colb = (unsigned)(kk * 64 + (lane >> 4) * 16);
#pragma unroll
            for (int mf = 0; mf < 2; ++mf)
                ar[mf] = *reinterpret_cast<const s16x8*>(sm.st.A + swz((unsigned)(wr * 32 + mf * 16 + (lane & 15)), colb));
#pragma unroll
            for (int nf = 0; nf < 4; ++nf)
                br[nf] = *reinterpret_cast<const s16x8*>(sm.st.B + swz((unsigned)(wc * 64 + nf * 16 + (lane & 15)), colb));
#pragma unroll
            for (int mf = 0; mf < 2; ++mf)
#pragma unroll
                for (int nf = 0; nf < 4; ++nf)
                    acc[mf][nf] = __builtin_amdgcn_mfma_f32_16x16x32_bf16(ar[mf], br[nf], acc[mf][nf], 0, 0, 0);
        }
    }
}

// shared epilogue: POST=0 direct bf16; POST=1 tile -> bf16 + int8; POST=2 tile -> int8 only
template<int ACT, int POST>
__device__ __forceinline__ void epi64(f32x4 (&acc)[2][4], const float* bias, SmU& sm,
                                      int m0, int M, int lane, int wave, int wr, int wc,
                                      unsigned short* outp, signed char* q, float* scl) {
    const int col0 = wc * 64 + (lane & 15);
    float bc[4];
#pragma unroll
    for (int nf = 0; nf < 4; ++nf) bc[nf] = bias[col0 + nf * 16];
    if (POST == 0) {
#pragma unroll
        for (int mf = 0; mf < 2; ++mf) {
            int row = m0 + wr * 32 + mf * 16 + (lane >> 4) * 4;
#pragma unroll
            for (int j = 0; j < 4; ++j) {
                if (row + j < M) {
#pragma unroll
                    for (int nf = 0; nf < 4; ++nf) {
                        float v = acc[mf][nf][j] + bc[nf];
                        if (ACT == 1) v = fmaxf(v, 0.0f);
                        else if (ACT == 2) v = v > 0.0f ? v : 0.01f * v;
                        outp[(size_t)(row + j) * DHID + col0 + nf * 16] = f2bf(v);
                    }
                }
            }
        }
        return;
    }
    __syncthreads();   // staging reads done before tile overwrites the union
#pragma unroll
    for (int mf = 0; mf < 2; ++mf) {
        int rl = wr * 32 + mf * 16 + (lane >> 4) * 4;
#pragma unroll
        for (int j = 0; j < 4; ++j)
#pragma unroll
            for (int nf = 0; nf < 4; ++nf) {
                float v = acc[mf][nf][j] + bc[nf];
                if (ACT == 1) v = fmaxf(v, 0.0f);
                else if (ACT == 2) v = v > 0.0f ? v : 0.01f * v;
                sm.tile[rl + j][col0 + nf * 16] = f2bf(v);
            }
    }
    __syncthreads();
    const int half = lane >> 5, l5 = lane & 31;
    for (int t = 0; t < 4; ++t) {
        int local = wave * 8 + half * 4 + t;
        int node = m0 + local;
        s16x8 tr = *reinterpret_cast<const s16x8*>(&sm.tile[local][l5 * 8]);
        float v[8]; float m = 0.0f;
#pragma unroll
        for (int j = 0; j < 8; ++j) { v[j] = bf2f((unsigned short)tr[j]); m = fmaxf(m, fabsf(v[j])); }
#pragma unroll
        for (int off = 1; off < 32; off <<= 1) m = fmaxf(m, __shfl_xor(m, off));
        if (node < M) {
            if (POST == 1)
                *reinterpret_cast<s16x8*>(outp + (size_t)node * DHID + l5 * 8) = tr;
            float si = (m > 0.0f) ? 127.0f / m : 0.0f;
            if (l5 == 0) scl[node] = m * (1.0f / 127.0f);
            uint2 pk;
            pk.x = ((unsigned)((int)__builtin_rintf(v[0] * si) & 255))
                 | ((unsigned)((int)__builtin_rintf(v[1] * si) & 255) << 8)
                 | ((unsigned)((int)__builtin_rintf(v[2] * si) & 255) << 16)
                 | ((unsigned)((int)__builtin_rintf(v[3] * si) & 255) << 24);
            pk.y = ((unsigned)((int)__builtin_rintf(v[4] * si) & 255))
                 | ((unsigned)((int)__builtin_rintf(v[5] * si) & 255) << 8)
                 | ((unsigned)((int)__builtin_rintf(v[6] * si) & 255) << 16)
                 | ((unsigned)((int)__builtin_rintf(v[7] * si) & 255) << 24);
            *reinterpret_cast<uint2*>(q + (size_t)node * DHID + l5 * 8) = pk;
        }
    }
}

template<int ACT, int FUSE, int POST>
__global__ __launch_bounds__(512) void mgemm64(const unsigned short* A1, const unsigned short* W1t,
                                               const float* __restrict__ bias,
                                               const unsigned short* A2, const unsigned short* W2t,
                                               unsigned short* outp, signed char* q, float* scl, int M) {
    __shared__ SmU sm;
    const int tid = threadIdx.x;
    const int lane = tid & 63, wave = tid >> 6;
    const int wr = wave >> 2, wc = wave & 3;
    const int m0 = blockIdx.x * 64;
    f32x4 acc[2][4];
#pragma unroll
    for (int a = 0; a < 2; ++a)
#pragma unroll
        for (int b = 0; b < 4; ++b) acc[a][b] = (f32x4)0.0f;
    pass64(A1, W1t, m0, M, lane, wave, wr, wc, acc, sm);
    if (FUSE) pass64(A2, W2t, m0, M, lane, wave, wr, wc, acc, sm);
    epi64<ACT, POST>(acc, bias, sm, m0, M, lane, wave, wr, wc, outp, q, scl);
}

// f32-A input projection, BM=64, K1 in {64,128}
template<int K1, int ACT, int POST>
__global__ __launch_bounds__(512) void mgemm64_f32(const float* __restrict__ A1, const unsigned short* W1t,
                                                   const float* __restrict__ bias,
                                                   unsigned short* outp, signed char* q, float* scl, int M) {
    __shared__ SmU sm;
    const int tid = threadIdx.x;
    const int lane = tid & 63, wave = tid >> 6;
    const int wr = wave >> 2, wc = wave & 3;
    const int m0 = blockIdx.x * 64;
    f32x4 acc[2][4];
#pragma unroll
    for (int a = 0; a < 2; ++a)
#pragma unroll
        for (int b = 0; b < 4; ++b) acc[a][b] = (f32x4)0.0f;

    for (int k0 = 0; k0 < K1; k0 += 64) {
        __syncthreads();
        {
            int r = tid >> 3, gc = tid & 7;
            int gr = m0 + r; if (gr >= M) gr = M - 1;
            const float* src = A1 + (size_t)gr * K1 + k0 + gc * 8;
            float4 v0 = *reinterpret_cast<const float4*>(src);
            float4 v1 = *reinterpret_cast<const float4*>(src + 4);
            s16x8 o;
            o[0] = (short)f2bf(v0.x); o[1] = (short)f2bf(v0.y);
            o[2] = (short)f2bf(v0.z); o[3] = (short)f2bf(v0.w);
            o[4] = (short)f2bf(v1.x); o[5] = (short)f2bf(v1.y);
            o[6] = (short)f2bf(v1.z); o[7] = (short)f2bf(v1.w);
            *reinterpret_cast<s16x8*>(sm.st.A + swz((unsigned)r, (unsigned)(gc * 16))) = o;
        }
#pragma unroll
        for (int i = 0; i < 4; ++i) {
            int u = wave * 4 + i;
            int nn = u * 8 + (lane >> 3);
            int gs = (lane & 7) ^ (nn & 7);
            gld16(W1t + (size_t)nn * K1 + k0 + gs * 8, sm.st.B + u * 1024);
        }
        __syncthreads();
#pragma unroll
        for (int kk = 0; kk < 2; ++kk) {
            s16x8 ar[2], br[4];
            unsigned colb = (unsigned)(kk * 64 + (lane >> 4) * 16);
#pragma unroll
            for (int mf = 0; mf < 2; ++mf)
                ar[mf] = *reinterpret_cast<const s16x8*>(sm.st.A + swz((unsigned)(wr * 32 + mf * 16 + (lane & 15)), colb));
#pragma unroll
            for (int nf = 0; nf < 4; ++nf)
                br[nf] = *reinterpret_cast<const s16x8*>(sm.st.B + swz((unsigned)(wc * 64 + nf * 16 + (lane & 15)), colb));
#pragma unroll
            for (int mf = 0; mf < 2; ++mf)
#pragma unroll
                for (int nf = 0; nf < 4; ++nf)
                    acc[mf][nf] = __builtin_amdgcn_mfma_f32_16x16x32_bf16(ar[mf], br[nf], acc[mf][nf], 0, 0, 0);
        }
    }
    epi64<ACT, POST>(acc, bias, sm, m0, M, lane, wave, wr, wc, outp, q, scl);
}

// ---------------- fused flow update, BM=64 ----------------
// HEAD=0: write F bf16.  HEAD=1: fuse output head, write logits [M][2] f32 (F not written).
template<int HEAD>
__global__ __launch_bounds__(512) void mgemm_faq(const unsigned short* Fin, const unsigned short* Wrt,
                                                 const float* __restrict__ bias,
                                                 const signed char* __restrict__ Hq,
                                                 const float* __restrict__ sclH,
                                                 const int* __restrict__ rowptr,
                                                 const int* __restrict__ colv,
                                                 unsigned short* Fout,
                                                 const float* __restrict__ linW,
                                                 const float* __restrict__ linb,
                                                 float* __restrict__ outHead, int M) {
    __shared__ SmU sm;
    const int tid = threadIdx.x;
    const int lane = tid & 63, wave = tid >> 6;
    const int wr = wave >> 2, wc = wave & 3;
    const int m0 = blockIdx.x * 64;
    f32x4 acc[2][4];
#pragma unroll
    for (int a = 0; a < 2; ++a)
#pragma unroll
        for (int b = 0; b < 4; ++b) acc[a][b] = (f32x4)0.0f;

    pass64(Fin, Wrt, m0, M, lane, wave, wr, wc, acc, sm);
    __syncthreads();   // staging reads done before tile overwrites the union

    const int col0 = wc * 64 + (lane & 15);
    float bc[4];
#pragma unroll
    for (int nf = 0; nf < 4; ++nf) bc[nf] = bias[col0 + nf * 16];
#pragma unroll
    for (int mf = 0; mf < 2; ++mf) {
        int rl = wr * 32 + mf * 16 + (lane >> 4) * 4;
#pragma unroll
        for (int j = 0; j < 4; ++j)
#pragma unroll
            for (int nf = 0; nf < 4; ++nf)
                sm.tile[rl + j][col0 + nf * 16] = f2bf(acc[mf][nf][j] + bc[nf]);
    }
    __syncthreads();

    const int half = lane >> 5, l5 = lane & 31;
    const signed char* base = Hq + l5 * 8;
    float w0[8], w1[8], hb0 = 0.0f, hb1 = 0.0f;
    if (HEAD) {
#pragma unroll
        for (int j = 0; j < 8; ++j) {
            w0[j] = linW[(l5 * 8 + j) * 2 + 0];
            w1[j] = linW[(l5 * 8 + j) * 2 + 1];
        }
        hb0 = linb[0]; hb1 = linb[1];
    }
    // gather phase: wave handles 8 nodes; halves alternate edges, 4-deep, int8 rows
    for (int t = 0; t < 8; ++t) {
        int local = wave * 8 + t;
        int node = m0 + local;
        if (node >= M) break;
        int beg = rowptr[node], end = rowptr[node + 1];
        int T = end - beg;
        int nb8 = T >> 3;
        float a0[8], a1[8], a2[8], a3[8];
#pragma unroll
        for (int j = 0; j < 8; ++j) { a0[j] = 0.f; a1[j] = 0.f; a2[j] = 0.f; a3[j] = 0.f; }
        const int* cp = colv + beg + half * 4;
        for (int k = 0; k < nb8; ++k) {
            int c0 = cp[k * 8 + 0], c1 = cp[k * 8 + 1], c2 = cp[k * 8 + 2], c3 = cp[k * 8 + 3];
            uint2 u0 = *reinterpret_cast<const uint2*>(base + (size_t)c0 * DHID);
            uint2 u1 = *reinterpret_cast<const uint2*>(base + (size_t)c1 * DHID);
            uint2 u2 = *reinterpret_cast<const uint2*>(base + (size_t)c2 * DHID);
            uint2 u3 = *reinterpret_cast<const uint2*>(base + (size_t)c3 * DHID);
            float s0 = sclH[c0], s1 = sclH[c1], s2 = sclH[c2], s3 = sclH[c3];
            dq8(u0, s0, a0); dq8(u1, s1, a1); dq8(u2, s2, a2); dq8(u3, s3, a3);
        }
        for (int i = beg + nb8 * 8 + half; i < end; i += 2) {
            int c = colv[i];
            uint2 u = *reinterpret_cast<const uint2*>(base + (size_t)c * DHID);
            dq8(u, sclH[c], a0);
        }
        float inv = 1.0f / (float)(T > 0 ? T : 1);
        s16x8 tr = *reinterpret_cast<const s16x8*>(&sm.tile[local][l5 * 8]);
        float v[8];
        s16x8 o;
#pragma unroll
        for (int j = 0; j < 8; ++j) {
            float s = (a0[j] + a1[j]) + (a2[j] + a3[j]);
            s += __shfl_xor(s, 32);
            float x = bf2f((unsigned short)tr[j]) + s * inv;
            x = x > 0.0f ? x : 0.01f * x;
            v[j] = x; o[j] = (short)f2bf(x);
        }
        if (HEAD) {
            float p0 = 0.0f, p1 = 0.0f;
#pragma unroll
            for (int j = 0; j < 8; ++j) { p0 += v[j] * w0[j]; p1 += v[j] * w1[j]; }
#pragma unroll
            for (int off = 1; off < 32; off <<= 1) {
                p0 += __shfl_xor(p0, off);
                p1 += __shfl_xor(p1, off);
            }
            if (lane == 0) {
                outHead[(size_t)node * 2 + 0] = p0 + hb0;
                outHead[(size_t)node * 2 + 1] = p1 + hb1;
            }
        } else {
            if (half == 0)
                *reinterpret_cast<s16x8*>(Fout + (size_t)node * DHID + l5 * 8) = o;
        }
    }
}

extern "C" void kernel_launch(void* const* d_in, const int* in_sizes, int n_in,
                              void* d_out, int out_size, void* d_ws, size_t ws_size,
                              hipStream_t stream) {
    const float* x_host  = (const float*)d_in[0];
    const float* x_flow  = (const float*)d_in[1];
    const int*   hf_src  = (const int*)d_in[2];
    const int*   hf_dst  = (const int*)d_in[3];
    const int*   fh_src  = (const int*)d_in[4];
    const int*   fh_dst  = (const int*)d_in[5];
    const float* host_W  = (const float*)d_in[6];
    const float* host_b  = (const float*)d_in[7];
    const float* flow_W  = (const float*)d_in[8];
    const float* flow_b  = (const float*)d_in[9];
    const float* Wl_hf   = (const float*)d_in[10];
    const float* bl_hf   = (const float*)d_in[11];
    const float* Wr_hf   = (const float*)d_in[12];
    const float* Wl_fh   = (const float*)d_in[13];
    const float* bl_fh   = (const float*)d_in[14];
    const float* Wr_fh   = (const float*)d_in[15];
    const float* lin_W   = (const float*)d_in[16];
    const float* lin_b   = (const float*)d_in[17];

    char* ws = (char*)d_ws;
    size_t off = 0;
    auto alloc = [&](size_t bytes) -> char* {
        char* p = ws + off;
        off += (bytes + 255) & ~(size_t)255;
        return p;
    };
    typedef unsigned short u16;
    u16* F     = (u16*)alloc((size_t)NF * DHID * 2);
    u16* H     = (u16*)alloc((size_t)NH * DHID * 2);
    u16* AggH  = (u16*)alloc((size_t)NH * DHID * 2);
    signed char* Fq = (signed char*)alloc((size_t)NF * DHID);
    signed char* Hq = (signed char*)alloc((size_t)NH * DHID);
    float* sclF = (float*)alloc((size_t)NF * 4);
    float* sclH = (float*)alloc((size_t)NH * 4);
    u16* hostWt = (u16*)alloc((size_t)DHID * DHOST * 2);
    u16* flowWt = (u16*)alloc((size_t)DHID * DFLOW * 2);
    u16* WlhfT  = (u16*)alloc((size_t)2 * DHID * DHID * 2);
    u16* WrhfT  = (u16*)alloc((size_t)2 * DHID * DHID * 2);
    u16* WlfhT  = (u16*)alloc((size_t)2 * DHID * DHID * 2);
    u16* WrfhT  = (u16*)alloc((size_t)2 * DHID * DHID * 2);
    float* zbias = (float*)alloc(DHID * 4);
    int* rp_hf  = (int*)alloc((size_t)(NF + 1) * 4);
    int* col_hf = (int*)alloc((size_t)NE * 4);
    int* rp_fh  = (int*)alloc((size_t)(NH + 1) * 4);
    int* col_fh = (int*)alloc((size_t)NE * 4);
    int* pairsA = (int*)alloc((size_t)NE * 4);
    int* pairsB = (int*)alloc((size_t)NE * 4);
    int* gbh2   = (int*)alloc(1024 * 4);
    int* bkoA   = (int*)alloc(513 * 4);
    int* bkoB   = (int*)alloc(513 * 4);
    int* gcurA  = (int*)alloc(512 * 4);
    int* gcurB  = (int*)alloc(512 * 4);
    int* junk   = (int*)alloc(4);
    int* gbhA = gbh2, *gbhB = gbh2 + 512;

    const int NBKT_HF = (NF + 511) / 512;   // 391
    const int NBKT_FH = (NH + 63) / 64;     // 313

    // ---- CSR build, both graphs overlapped ----
    zero_k<<<4, 256, 0, stream>>>(gbh2, 1024);
    histAB<<<dim3((NE + 2047) / 2048, 2), 256, 0, stream>>>(hf_dst, fh_dst, NE, gbhA, gbhB);
    scan1_k<<<1, 256, 0, stream>>>(gbhA, NBKT_HF, bkoA, junk);
    scan1_k<<<1, 256, 0, stream>>>(gbhB, NBKT_FH, bkoB, junk);
    initcur_k<<<2, 256, 0, stream>>>(bkoA, gcurA, NBKT_HF, NE);
    initcur_k<<<2, 256, 0, stream>>>(bkoB, gcurB, NBKT_FH, NE);
    binpassAB<<<dim3((NE + 8191) / 8192, 2), 256, 0, stream>>>(hf_src, hf_dst, fh_src, fh_dst, NE,
                                                               gcurA, gcurB, pairsA, pairsB);
    csrfinAB<<<NBKT_HF + NBKT_FH, 256, 0, stream>>>(pairsA, bkoA, pairsB, bkoB, NBKT_HF, NE,
                                                    rp_hf, col_hf, rp_fh, col_fh);

    // ---- weights to bf16 (transposed); zero bias ----
    zero_k<<<1, 256, 0, stream>>>((int*)zbias, DHID);
    tpose_k<<<dim3(8, DHOST / 32, 1), 256, 0, stream>>>(host_W, hostWt, DHOST);
    tpose_k<<<dim3(8, DFLOW / 32, 1), 256, 0, stream>>>(flow_W, flowWt, DFLOW);
    tpose_k<<<dim3(8, 8, 2), 256, 0, stream>>>(Wl_hf, WlhfT, DHID);
    tpose_k<<<dim3(8, 8, 2), 256, 0, stream>>>(Wr_hf, WrhfT, DHID);
    tpose_k<<<dim3(8, 8, 2), 256, 0, stream>>>(Wl_fh, WlfhT, DHID);
    tpose_k<<<dim3(8, 8, 2), 256, 0, stream>>>(Wr_fh, WrfhT, DHID);

    // ---- input projections (relu); flow also emits int8 Fq for layer-0 fh-agg ----
    mgemm64_f32<DHOST, 1, 0><<<(NH + 63) / 64, 512, 0, stream>>>(x_host, hostWt, host_b, H, nullptr, nullptr, NH);
    mgemm64_f32<DFLOW, 1, 1><<<(NF + 63) / 64, 512, 0, stream>>>(x_flow, flowWt, flow_b, F, Fq, sclF, NF);

    // ---- layer 0 (full: flow + host updates) ----
    {
        const u16* wl_hf = WlhfT;
        const u16* wr_hf = WrhfT;
        const u16* wl_fh = WlfhT;
        const u16* wr_fh = WrfhT;

        // Hq = int8(H @ Wl_hf)
        mgemm64<0, 0, 2><<<(NH + 63) / 64, 512, 0, stream>>>(H, wl_hf, zbias, H, wl_hf,
                                                             nullptr, Hq, sclH, NH);
        // AggH = mean_agg(f_old) over fh graph (feeds the live layer-0 host update)
        agg8_q8<<<(NH + 3) / 4, 256, 0, stream>>>(Fq, sclF, rp_fh, col_fh, AggH, NH);
        // flow update in place on F
        mgemm_faq<0><<<(NF + 63) / 64, 512, 0, stream>>>(F, wr_hf, bl_hf, Hq, sclH,
                                                         rp_hf, col_hf, F,
                                                         nullptr, nullptr, nullptr, NF);
        // host update in place on H
        mgemm64<2, 1, 0><<<(NH + 63) / 64, 512, 0, stream>>>(AggH, wl_fh, bl_fh, H, wr_fh,
                                                             H, nullptr, nullptr, NH);
    }

    // ---- layer 1 (host-side update is dead code: output head only reads f) ----
    {
        const u16* wl_hf = WlhfT + (size_t)DHID * DHID;
        const u16* wr_hf = WrhfT + (size_t)DHID * DHID;
        const float* b_hf = bl_hf + DHID;

        // Hq = int8(H @ Wl_hf[1])
        mgemm64<0, 0, 2><<<(NH + 63) / 64, 512, 0, stream>>>(H, wl_hf, zbias, H, wl_hf,
                                                             nullptr, Hq, sclH, NH);
        // flow update fused with the output head: writes logits directly
        mgemm_faq<1><<<(NF + 63) / 64, 512, 0, stream>>>(F, wr_hf, b_hf, Hq, sclH,
                                                         rp_hf, col_hf, nullptr,
                                                         lin_W, lin_b, (float*)d_out, NF);
    }
}